// Round 1
// 349.677 us; speedup vs baseline: 1.0101x; 1.0101x over previous
//
#include <hip/hip_runtime.h>
#include <cstdint>
#include <cstddef>

// ---------------------------------------------------------------------------
// MultiHeadAttention: B=4, T=2048, D=1024, H=16, DH=64
// Round 5: GEMMs rewritten as 256x128-tile, BK=64, 8-wave pipelined kernels:
//  - 3-buffer LDS rotation (144 KiB), prefetch depth 2, counted vmcnt(12)
//    before raw s_barrier (never drain to 0 in the main loop)  [T3+T4]
//  - XOR chunk swizzle (chunk ^ row&7), pre-swizzled global src  [T2]
//  - s_setprio(1) around MFMA clusters                           [T5]
// Attention + cast unchanged from R3/R4.
// ---------------------------------------------------------------------------

typedef float f32x4 __attribute__((ext_vector_type(4)));
typedef short bf16x8 __attribute__((ext_vector_type(8)));
typedef float fltx4 __attribute__((ext_vector_type(4)));
typedef unsigned short u16x4 __attribute__((ext_vector_type(4)));

#define GLOBAL_AS __attribute__((address_space(1)))
#define LDS_AS __attribute__((address_space(3)))

__device__ __forceinline__ unsigned short f2bf(float f) {
    union { float f; unsigned int u; } x;
    x.f = f;
    unsigned int u = x.u;
    unsigned int r = (u + 0x7FFFu + ((u >> 16) & 1u)) >> 16;  // RNE
    return (unsigned short)r;
}

__device__ __forceinline__ unsigned int pack_trunc(float a, float b) {
    union { float f; unsigned int u; } x, y;
    x.f = a; y.f = b;
    return (x.u >> 16) | (y.u & 0xFFFF0000u);  // bf16 trunc; rel err < 2^-8
}

// ---------------------------------------------------------------------------
// Cast kernel: q,k,v (8M each) + wq,wk,wv,wo (1M each) f32 -> bf16.
// ---------------------------------------------------------------------------
__global__ __launch_bounds__(256) void cast_all_kernel(
    const float* __restrict__ q, const float* __restrict__ k, const float* __restrict__ v,
    const float* __restrict__ wq, const float* __restrict__ wk,
    const float* __restrict__ wv, const float* __restrict__ wo,
    unsigned short* __restrict__ dst)
{
    const size_t SEG = 8388608;   // B*T*D
    const size_t WSEG = 1048576;  // D*D
    size_t i = ((size_t)blockIdx.x * 256 + threadIdx.x) * 4;
    const float* src;
    size_t off;
    if (i < SEG)               { src = q;  off = i; }
    else if (i < 2 * SEG)      { src = k;  off = i - SEG; }
    else if (i < 3 * SEG)      { src = v;  off = i - 2 * SEG; }
    else if (i < 3 * SEG + WSEG)     { src = wq; off = i - 3 * SEG; }
    else if (i < 3 * SEG + 2 * WSEG) { src = wk; off = i - 3 * SEG - WSEG; }
    else if (i < 3 * SEG + 3 * WSEG) { src = wv; off = i - 3 * SEG - 2 * WSEG; }
    else                             { src = wo; off = i - 3 * SEG - 3 * WSEG; }
    fltx4 val = *(const fltx4*)(src + off);
    u16x4 o;
    o[0] = f2bf(val[0]);
    o[1] = f2bf(val[1]);
    o[2] = f2bf(val[2]);
    o[3] = f2bf(val[3]);
    *(u16x4*)(dst + i) = o;
}

// ---------------------------------------------------------------------------
// Pipelined GEMM core as a macro-free inline pattern, instantiated in both
// GEMM kernels via lambdas (keeps LDS in addrspace(3) for ds_read_b128).
//
// Geometry: BM=256, BN=128, BK=64, 8 waves (512 thr), wave tile 64x64.
// LDS per buffer: A 256x64 bf16 (32KB) + B 128x64 bf16 (16KB) = 48KB.
// 3 buffers = 144KB. Per wave per K-tile: 4 A-loads + 2 B-loads (16B/lane).
// Swizzle: LDS slot (row, c) holds global chunk c ^ (row&7); read applies
// the same XOR (involution), so ds_read_b128 is ~2-way on banks (free).
// ---------------------------------------------------------------------------

// ---------------------------------------------------------------------------
// Fused QKV GEMM: z = blockIdx.y in {0,1,2} selects Q/K/V projection.
// ---------------------------------------------------------------------------
__global__ __launch_bounds__(512, 2) void qkv_gemm_kernel(
    const unsigned short* __restrict__ X,    // xq base; xk=+8M, xv=+16M
    const unsigned short* __restrict__ Wc,   // wqc base; wkc=+1M, wvc=+2M
    const float* __restrict__ bq, const float* __restrict__ bk,
    const float* __restrict__ bv,
    unsigned short* __restrict__ Outs,       // Qhp base; Khp=+8M, Vtp=+16M
    float qscale)
{
    const int z = blockIdx.y;
    const unsigned short* A  = X  + (size_t)z * 8388608;
    const unsigned short* Bw = Wc + (size_t)z * 1048576;
    const float* bias = (z == 0) ? bq : (z == 1) ? bk : bv;
    unsigned short* outp = Outs + (size_t)z * 8388608;
    const float scale = (z == 0) ? qscale : 1.0f;
    const bool vmode = (z == 2);

    __shared__ __align__(16) unsigned short lds[3 * 24576];

    const int tid = threadIdx.x;
    const int w = tid >> 6, lane = tid & 63;
    const int quad = lane >> 4, l16 = lane & 15;
    const int wr = w >> 1, wc = w & 1;

    // XCD banding: XCD r_ owns M-rows [r_*1024, r_*1024+1024): A band 2MB +
    // weights 2MB = L2 size. 256 tiles/z; z slices start at lin % 8 == 0.
    const int lin = blockIdx.x;
    const int r_ = lin & 7, s_ = lin >> 3;
    const int bm = (r_ * 4 + (s_ & 3)) * 256;
    const int bn = (s_ >> 2) * 128;

    const int rsub = lane >> 3;            // 0..7: row within 8-row group
    const int csw = (lane & 7) ^ rsub;     // pre-swizzled global chunk

    auto stage = [&](int kt, int buf) {
        unsigned short* lA = lds + buf * 24576;
        unsigned short* lB = lA + 16384;
        const unsigned short* Ab = A + (size_t)bm * 1024 + kt * 64;
        const unsigned short* Bb = Bw + (size_t)bn * 1024 + kt * 64;
#pragma unroll
        for (int j = 0; j < 4; ++j) {
            int r0 = w * 32 + j * 8;
            __builtin_amdgcn_global_load_lds(
                (const GLOBAL_AS unsigned int*)(Ab + (size_t)(r0 + rsub) * 1024 + csw * 8),
                (LDS_AS unsigned int*)(lA + r0 * 64), 16, 0, 0);
        }
#pragma unroll
        for (int j = 0; j < 2; ++j) {
            int r0 = w * 16 + j * 8;
            __builtin_amdgcn_global_load_lds(
                (const GLOBAL_AS unsigned int*)(Bb + (size_t)(r0 + rsub) * 1024 + csw * 8),
                (LDS_AS unsigned int*)(lB + r0 * 64), 16, 0, 0);
        }
    };

    f32x4 acc[4][4] = {};

    stage(0, 0);
    stage(1, 1);

    for (int kt = 0; kt < 16; ++kt) {
        const int cur = kt % 3;
        if (kt < 14) {
            stage(kt + 2, (kt + 2) % 3);   // buffer last read at iter kt-1
            asm volatile("s_waitcnt vmcnt(12)" ::: "memory");  // tile kt landed
        } else if (kt == 14) {
            asm volatile("s_waitcnt vmcnt(6)" ::: "memory");
        } else {
            asm volatile("s_waitcnt vmcnt(0)" ::: "memory");
        }
        __builtin_amdgcn_s_barrier();
        __builtin_amdgcn_sched_barrier(0);

        const unsigned short* lA = lds + cur * 24576;
        const unsigned short* lB = lA + 16384;
#pragma unroll
        for (int kh = 0; kh < 2; ++kh) {
            bf16x8 af[4], bfr[4];
#pragma unroll
            for (int mi = 0; mi < 4; ++mi) {
                int row = wr * 64 + mi * 16 + l16;
                af[mi] = *(const bf16x8*)(lA + (size_t)row * 64 +
                                          (((kh * 4 + quad) ^ (row & 7)) * 8));
            }
#pragma unroll
            for (int ni = 0; ni < 4; ++ni) {
                int row = wc * 64 + ni * 16 + l16;
                bfr[ni] = *(const bf16x8*)(lB + (size_t)row * 64 +
                                           (((kh * 4 + quad) ^ (row & 7)) * 8));
            }
            __builtin_amdgcn_s_setprio(1);
#pragma unroll
            for (int mi = 0; mi < 4; ++mi)
#pragma unroll
                for (int ni = 0; ni < 4; ++ni)
                    acc[mi][ni] = __builtin_amdgcn_mfma_f32_16x16x32_bf16(
                        af[mi], bfr[ni], acc[mi][ni], 0, 0, 0);
            __builtin_amdgcn_s_setprio(0);
        }
        __builtin_amdgcn_sched_barrier(0);
        __builtin_amdgcn_s_barrier();      // all waves done reading buf[cur]
    }

#pragma unroll
    for (int mi = 0; mi < 4; ++mi) {
        int rowb = bm + wr * 64 + mi * 16 + quad * 4;
#pragma unroll
        for (int ni = 0; ni < 4; ++ni) {
            int col = bn + wc * 64 + ni * 16 + l16;
            float bv_ = bias[col];
#pragma unroll
            for (int r = 0; r < 4; ++r) {
                int m = rowb + r;
                float vout = (acc[mi][ni][r] + bv_) * scale;
                int b = m >> 11, t = m & 2047, h = col >> 6, d = col & 63;
                if (!vmode) {
                    outp[((size_t)(b * 16 + h) * 2048 + t) * 64 + d] = f2bf(vout);
                } else {
                    outp[((size_t)(b * 16 + h) * 64 + d) * 2048 + t] = f2bf(vout);
                }
            }
        }
    }
}

// ---------------------------------------------------------------------------
// Output-projection GEMM (f32 out), same pipelined core.
// ---------------------------------------------------------------------------
__global__ __launch_bounds__(512, 2) void out_gemm_kernel(
    const unsigned short* __restrict__ A,
    const unsigned short* __restrict__ Bw,
    const float* __restrict__ bias,
    float* __restrict__ outp)
{
    __shared__ __align__(16) unsigned short lds[3 * 24576];

    const int tid = threadIdx.x;
    const int w = tid >> 6, lane = tid & 63;
    const int quad = lane >> 4, l16 = lane & 15;
    const int wr = w >> 1, wc = w & 1;

    const int lin = blockIdx.x;
    const int r_ = lin & 7, s_ = lin >> 3;
    const int bm = (r_ * 4 + (s_ & 3)) * 256;
    const int bn = (s_ >> 2) * 128;

    const int rsub = lane >> 3;
    const int csw = (lane & 7) ^ rsub;

    auto stage = [&](int kt, int buf) {
        unsigned short* lA = lds + buf * 24576;
        unsigned short* lB = lA + 16384;
        const unsigned short* Ab = A + (size_t)bm * 1024 + kt * 64;
        const unsigned short* Bb = Bw + (size_t)bn * 1024 + kt * 64;
#pragma unroll
        for (int j = 0; j < 4; ++j) {
            int r0 = w * 32 + j * 8;
            __builtin_amdgcn_global_load_lds(
                (const GLOBAL_AS unsigned int*)(Ab + (size_t)(r0 + rsub) * 1024 + csw * 8),
                (LDS_AS unsigned int*)(lA + r0 * 64), 16, 0, 0);
        }
#pragma unroll
        for (int j = 0; j < 2; ++j) {
            int r0 = w * 16 + j * 8;
            __builtin_amdgcn_global_load_lds(
                (const GLOBAL_AS unsigned int*)(Bb + (size_t)(r0 + rsub) * 1024 + csw * 8),
                (LDS_AS unsigned int*)(lB + r0 * 64), 16, 0, 0);
        }
    };

    f32x4 acc[4][4] = {};

    stage(0, 0);
    stage(1, 1);

    for (int kt = 0; kt < 16; ++kt) {
        const int cur = kt % 3;
        if (kt < 14) {
            stage(kt + 2, (kt + 2) % 3);
            asm volatile("s_waitcnt vmcnt(12)" ::: "memory");
        } else if (kt == 14) {
            asm volatile("s_waitcnt vmcnt(6)" ::: "memory");
        } else {
            asm volatile("s_waitcnt vmcnt(0)" ::: "memory");
        }
        __builtin_amdgcn_s_barrier();
        __builtin_amdgcn_sched_barrier(0);

        const unsigned short* lA = lds + cur * 24576;
        const unsigned short* lB = lA + 16384;
#pragma unroll
        for (int kh = 0; kh < 2; ++kh) {
            bf16x8 af[4], bfr[4];
#pragma unroll
            for (int mi = 0; mi < 4; ++mi) {
                int row = wr * 64 + mi * 16 + l16;
                af[mi] = *(const bf16x8*)(lA + (size_t)row * 64 +
                                          (((kh * 4 + quad) ^ (row & 7)) * 8));
            }
#pragma unroll
            for (int ni = 0; ni < 4; ++ni) {
                int row = wc * 64 + ni * 16 + l16;
                bfr[ni] = *(const bf16x8*)(lB + (size_t)row * 64 +
                                           (((kh * 4 + quad) ^ (row & 7)) * 8));
            }
            __builtin_amdgcn_s_setprio(1);
#pragma unroll
            for (int mi = 0; mi < 4; ++mi)
#pragma unroll
                for (int ni = 0; ni < 4; ++ni)
                    acc[mi][ni] = __builtin_amdgcn_mfma_f32_16x16x32_bf16(
                        af[mi], bfr[ni], acc[mi][ni], 0, 0, 0);
            __builtin_amdgcn_s_setprio(0);
        }
        __builtin_amdgcn_sched_barrier(0);
        __builtin_amdgcn_s_barrier();
    }

#pragma unroll
    for (int mi = 0; mi < 4; ++mi) {
        int rowb = bm + wr * 64 + mi * 16 + quad * 4;
#pragma unroll
        for (int ni = 0; ni < 4; ++ni) {
            int col = bn + wc * 64 + ni * 16 + l16;
            float bv_ = bias[col];
#pragma unroll
            for (int r = 0; r < 4; ++r)
                outp[(size_t)(rowb + r) * 1024 + col] = acc[mi][ni][r] + bv_;
        }
    }
}

// ---------------------------------------------------------------------------
// Flash attention v3 (causal, m=0 softmax, paired blocks). Unchanged from R3.
// ---------------------------------------------------------------------------
__global__ __launch_bounds__(256) void attn_kernel(
    const unsigned short* __restrict__ Qh,
    const unsigned short* __restrict__ Kh,
    const unsigned short* __restrict__ Vt,
    unsigned short* __restrict__ att)
{
    const int tid = threadIdx.x;
    const int w = tid >> 6, lane = tid & 63;
    const int qd = lane >> 4, l16 = lane & 15;
    const int bh = blockIdx.x;    // 0..63 (same-bh blocks -> same XCD)
    const int pairy = blockIdx.y; // 0..7

    const unsigned short* Qp = Qh + (size_t)bh * 2048 * 64;
    const unsigned short* Kp = Kh + (size_t)bh * 2048 * 64;
    const unsigned short* Vp = Vt + (size_t)bh * 64 * 2048;
    const int b = bh >> 4, h = bh & 15;

    __shared__ __align__(16) unsigned short Kl[2][64 * 64];
    __shared__ __align__(16) unsigned short Vl[2][64 * 64];
    __shared__ __align__(16) unsigned short Pl[4][2][16 * 64];

    auto stage = [&](int kt, int buf) {
#pragma unroll
        for (int j = 0; j < 2; ++j) {
            int r = w * 16 + j * 8 + (lane >> 3);
            int c = (lane & 7) ^ (r & 7);
            __builtin_amdgcn_global_load_lds(
                (const GLOBAL_AS unsigned int*)(Kp + (size_t)(kt * 64 + r) * 64 + c * 8),
                (LDS_AS unsigned int*)(&Kl[buf][(w * 16 + j * 8) * 64]), 16, 0, 0);
            __builtin_amdgcn_global_load_lds(
                (const GLOBAL_AS unsigned int*)(Vp + (size_t)r * 2048 + kt * 64 + c * 8),
                (LDS_AS unsigned int*)(&Vl[buf][(w * 16 + j * 8) * 64]), 16, 0, 0);
        }
    };

    auto run_phase = [&](int qblk) {
        const int wqbase = qblk * 128 + w * 32;
        const int ktmax = 2 * qblk + 1;

        bf16x8 qa[2][2];
#pragma unroll
        for (int qt = 0; qt < 2; ++qt)
#pragma unroll
            for (int ks = 0; ks < 2; ++ks)
                qa[qt][ks] = *(const bf16x8*)(Qp + (size_t)(wqbase + qt * 16 + l16) * 64 + ks * 32 + qd * 8);

        float lp[2] = {0.0f, 0.0f};
        f32x4 O[2][4] = {};

        __syncthreads();  // prior phase's LDS reads complete before restaging
        stage(0, 0);

        for (int kt = 0; kt <= ktmax; ++kt) {
            __syncthreads();  // implicit vmcnt(0): buf[kt&1] staged
            if (kt < ktmax) stage(kt + 1, (kt + 1) & 1);

            if (kt * 64 <= wqbase + 31) {  // wave-uniform skip of masked tiles
                const unsigned short* kl = &Kl[kt & 1][0];
                const unsigned short* vl = &Vl[kt & 1][0];

                bf16x8 kf[4][2];
#pragma unroll
                for (int nt = 0; nt < 4; ++nt)
#pragma unroll
                    for (int ks = 0; ks < 2; ++ks)
                        kf[nt][ks] = *(const bf16x8*)(kl + (nt * 16 + l16) * 64 +
                                                      (((ks * 4 + qd) ^ (l16 & 7)) * 8));

                f32x4 S[2][4];
#pragma unroll
                for (int qt = 0; qt < 2; ++qt)
#pragma unroll
                    for (int nt = 0; nt < 4; ++nt) {
                        f32x4 a = {};
                        a = __builtin_amdgcn_mfma_f32_16x16x32_bf16(kf[nt][0], qa[qt][0], a, 0, 0, 0);
                        a = __builtin_amdgcn_mfma_f32_16x16x32_bf16(kf[nt][1], qa[qt][1], a, 0, 0, 0);
                        S[qt][nt] = a;
                    }

                if (kt * 64 + 63 > wqbase) {
#pragma unroll
                    for (int qt = 0; qt < 2; ++qt) {
                        int qrow = wqbase + qt * 16 + l16;
#pragma unroll
                        for (int nt = 0; nt < 4; ++nt) {
                            int kbase = kt * 64 + nt * 16 + qd * 4;
#pragma unroll
                            for (int r = 0; r < 4; ++r)
                                if (kbase + r > qrow) S[qt][nt][r] = -INFINITY;
                        }
                    }
                }

#pragma unroll
                for (int qt = 0; qt < 2; ++qt) {
                    float s0 = 0.0f;
#pragma unroll
                    for (int nt = 0; nt < 4; ++nt)
#pragma unroll
                        for (int r = 0; r < 4; ++r) {
                            float e = __builtin_amdgcn_exp2f(S[qt][nt][r]);
                            S[qt][nt][r] = e;
                            s0 += e;
                        }
                    lp[qt] += s0;
                }

#pragma unroll
                for (int qt = 0; qt < 2; ++qt) {
                    unsigned short* pw = &Pl[w][qt][0];
#pragma unroll
                    for (int nt = 0; nt < 4; ++nt) {
                        uint2 pv;
                        pv.x = pack_trunc(S[qt][nt][0], S[qt][nt][1]);
                        pv.y = pack_trunc(S[qt][nt][2], S[qt][nt][3]);
                        int chunk = (2 * nt + (qd >> 1)) ^ (l16 & 7);
                        *(uint2*)(pw + l16 * 64 + chunk * 8 + (qd & 1) * 4) = pv;
                    }
                }
                asm volatile("s_waitcnt lgkmcnt(0)" ::: "memory");

                bf16x8 pa[2][2];
#pragma unroll
                for (int qt = 0; qt < 2; ++qt)
#pragma unroll
                    for (int s = 0; s < 2; ++s)
                        pa[qt][s] = *(const bf16x8*)(&Pl[w][qt][0] + l16 * 64 +
                                                     (((s * 4 + qd) ^ (l16 & 7)) * 8));

                bf16x8 vf[2][4];
#pragma unroll
                for (int s = 0; s < 2; ++s)
#pragma unroll
                    for (int dh = 0; dh < 4; ++dh)
                        vf[s][dh] = *(const bf16x8*)(vl + (dh * 16 + l16) * 64 +
                                                     (((s * 4 + qd) ^ (l16 & 7)) * 8));
#pragma unroll
                for (int qt = 0; qt < 2; ++qt)
#pragma unroll
                    for (int dh = 0; dh < 4; ++dh) {
                        O[qt][dh] = __builtin_amdgcn_mfma_f32_16x16x32_bf16(pa[qt][0], vf[0][dh], O[qt][dh], 0, 0, 0);
                        O[qt][dh] = __builtin_amdgcn_mfma_f32_16x16x32_bf16(pa[qt][1], vf[1][dh], O[qt][dh], 0, 0, 0);
                    }
            }
        }

#pragma unroll
        for (int qt = 0; qt < 2; ++qt) {
            float lsum = lp[qt];
            lsum += __shfl_xor(lsum, 16, 64);
            lsum += __shfl_xor(lsum, 32, 64);
            float linv = 1.0f / lsum;
#pragma unroll
            for (int r = 0; r < 4; ++r) {
                float lC = __shfl(linv, qd * 4 + r, 64);
                int t = wqbase + qt * 16 + qd * 4 + r;
#pragma unroll
                for (int dh = 0; dh < 4; ++dh) {
                    size_t idx = (size_t)(b * 2048 + t) * 1024 + h * 64 + dh * 16 + l16;
                    att[idx] = f2bf(O[qt][dh][r] * lC);
                }
            }
        }
    };

    run_phase(15 - pairy);  // heavy half
    run_phase(pairy);       // light half -> uniform 36 tiles per block
}

// ---------------------------------------------------------------------------
// Launch
// ---------------------------------------------------------------------------
extern "C" void kernel_launch(void* const* d_in, const int* in_sizes, int n_in,
                              void* d_out, int out_size, void* d_ws, size_t ws_size,
                              hipStream_t stream)
{
    const float* q = (const float*)d_in[0];
    const float* k = (const float*)d_in[1];
    const float* v = (const float*)d_in[2];
    const float* wq_w = (const float*)d_in[5];
    const float* wq_b = (const float*)d_in[6];
    const float* wk_w = (const float*)d_in[7];
    const float* wk_b = (const float*)d_in[8];
    const float* wv_w = (const float*)d_in[9];
    const float* wv_b = (const float*)d_in[10];
    const float* wo_w = (const float*)d_in[11];
    const float* wo_b = (const float*)d_in[12];

    unsigned short* ws = (unsigned short*)d_ws;
    unsigned short* xq  = ws;                    // 8M
    unsigned short* wqc = ws + 25165824;         // wq,wk,wv contiguous 1M each
    unsigned short* woc = ws + 28311552;
    unsigned short* Qhp = ws + 29360128;         // Qh,Kh,Vt contiguous 8M each
    unsigned short* Khp = ws + 37748736;
    unsigned short* Vtp = ws + 46137344;
    unsigned short* att = xq;  // xq dead after QKV projections

    (void)in_sizes; (void)n_in; (void)out_size; (void)ws_size;

    cast_all_kernel<<<28672, 256, 0, stream>>>(q, k, v, wq_w, wk_w, wv_w, wo_w, ws);

    qkv_gemm_kernel<<<dim3(256, 3), 512, 0, stream>>>(
        xq, wqc, wq_b, wk_b, wv_b, Qhp, 0.1803368801f);

    attn_kernel<<<dim3(64, 8), 256, 0, stream>>>(Qhp, Khp, Vtp, att);

    out_gemm_kernel<<<dim3(256), 512, 0, stream>>>(att, woc, wo_b, (float*)d_out);
}

// Round 2
// 344.437 us; speedup vs baseline: 1.0255x; 1.0152x over previous
//
#include <hip/hip_runtime.h>
#include <cstdint>
#include <cstddef>

// ---------------------------------------------------------------------------
// MultiHeadAttention: B=4, T=2048, D=1024, H=16, DH=64
// Round 6:
//  - GEMMs: true per-phase interleave (2 phases per K-tile, one per kh half):
//    {8 ds_read ∥ 3 stage loads → barrier → lgkmcnt(0)+sched_barrier →
//     setprio(1) 16 MFMA setprio(0) → barrier}; counted vmcnt(6) once per
//    tile end (never 0 in steady state). 3-buffer rotation, depth-2 prefetch.
//  - attn: replace per-tile __syncthreads (vmcnt(0) drain) with 3-buffer
//    depth-2 prefetch + counted vmcnt(4) + raw s_barrier; stage issued after
//    the barrier (all waves have finished previous tile's LDS reads).
// Numerics (accumulation order) identical to R5.
// ---------------------------------------------------------------------------

typedef float f32x4 __attribute__((ext_vector_type(4)));
typedef short bf16x8 __attribute__((ext_vector_type(8)));
typedef float fltx4 __attribute__((ext_vector_type(4)));
typedef unsigned short u16x4 __attribute__((ext_vector_type(4)));

#define GLOBAL_AS __attribute__((address_space(1)))
#define LDS_AS __attribute__((address_space(3)))

__device__ __forceinline__ unsigned short f2bf(float f) {
    union { float f; unsigned int u; } x;
    x.f = f;
    unsigned int u = x.u;
    unsigned int r = (u + 0x7FFFu + ((u >> 16) & 1u)) >> 16;  // RNE
    return (unsigned short)r;
}

__device__ __forceinline__ unsigned int pack_trunc(float a, float b) {
    union { float f; unsigned int u; } x, y;
    x.f = a; y.f = b;
    return (x.u >> 16) | (y.u & 0xFFFF0000u);  // bf16 trunc; rel err < 2^-8
}

// ---------------------------------------------------------------------------
// Cast kernel: q,k,v (8M each) + wq,wk,wv,wo (1M each) f32 -> bf16.
// ---------------------------------------------------------------------------
__global__ __launch_bounds__(256) void cast_all_kernel(
    const float* __restrict__ q, const float* __restrict__ k, const float* __restrict__ v,
    const float* __restrict__ wq, const float* __restrict__ wk,
    const float* __restrict__ wv, const float* __restrict__ wo,
    unsigned short* __restrict__ dst)
{
    const size_t SEG = 8388608;   // B*T*D
    const size_t WSEG = 1048576;  // D*D
    size_t i = ((size_t)blockIdx.x * 256 + threadIdx.x) * 4;
    const float* src;
    size_t off;
    if (i < SEG)               { src = q;  off = i; }
    else if (i < 2 * SEG)      { src = k;  off = i - SEG; }
    else if (i < 3 * SEG)      { src = v;  off = i - 2 * SEG; }
    else if (i < 3 * SEG + WSEG)     { src = wq; off = i - 3 * SEG; }
    else if (i < 3 * SEG + 2 * WSEG) { src = wk; off = i - 3 * SEG - WSEG; }
    else if (i < 3 * SEG + 3 * WSEG) { src = wv; off = i - 3 * SEG - 2 * WSEG; }
    else                             { src = wo; off = i - 3 * SEG - 3 * WSEG; }
    fltx4 val = *(const fltx4*)(src + off);
    u16x4 o;
    o[0] = f2bf(val[0]);
    o[1] = f2bf(val[1]);
    o[2] = f2bf(val[2]);
    o[3] = f2bf(val[3]);
    *(u16x4*)(dst + i) = o;
}

// ---------------------------------------------------------------------------
// Fused QKV GEMM: z = blockIdx.y in {0,1,2} selects Q/K/V projection.
// BM=256, BN=128, BK=64, 8 waves (4Mx2N), wave tile 64x64.
// ---------------------------------------------------------------------------
__global__ __launch_bounds__(512, 2) void qkv_gemm_kernel(
    const unsigned short* __restrict__ X,    // xq base; xk=+8M, xv=+16M
    const unsigned short* __restrict__ Wc,   // wqc base; wkc=+1M, wvc=+2M
    const float* __restrict__ bq, const float* __restrict__ bk,
    const float* __restrict__ bv,
    unsigned short* __restrict__ Outs,       // Qhp base; Khp=+8M, Vtp=+16M
    float qscale)
{
    const int z = blockIdx.y;
    const unsigned short* A  = X  + (size_t)z * 8388608;
    const unsigned short* Bw = Wc + (size_t)z * 1048576;
    const float* bias = (z == 0) ? bq : (z == 1) ? bk : bv;
    unsigned short* outp = Outs + (size_t)z * 8388608;
    const float scale = (z == 0) ? qscale : 1.0f;
    const bool vmode = (z == 2);

    __shared__ __align__(16) unsigned short lds[3 * 24576];

    const int tid = threadIdx.x;
    const int w = tid >> 6, lane = tid & 63;
    const int quad = lane >> 4, l16 = lane & 15;
    const int wr = w >> 1, wc = w & 1;

    // XCD banding: XCD r_ owns M-rows [r_*1024, +1024): A band 2MB + W 2MB.
    const int lin = blockIdx.x;
    const int r_ = lin & 7, s_ = lin >> 3;
    const int bm = (r_ * 4 + (s_ & 3)) * 256;
    const int bn = (s_ >> 2) * 128;

    const int rsub = lane >> 3;            // 0..7: row within 8-row group
    const int csw = (lane & 7) ^ rsub;     // pre-swizzled global chunk

    // half 0: A rows [w*32, +16) + B rows [w*16, +8); half 1: the rest.
    auto stage_half = [&](int kt, int buf, int half) {
        unsigned short* lA = lds + buf * 24576;
        unsigned short* lB = lA + 16384;
        const unsigned short* Ab = A + (size_t)bm * 1024 + kt * 64;
        const unsigned short* Bb = Bw + (size_t)bn * 1024 + kt * 64;
#pragma unroll
        for (int j = 0; j < 2; ++j) {
            int r0 = w * 32 + (half * 2 + j) * 8;
            __builtin_amdgcn_global_load_lds(
                (const GLOBAL_AS unsigned int*)(Ab + (size_t)(r0 + rsub) * 1024 + csw * 8),
                (LDS_AS unsigned int*)(lA + r0 * 64), 16, 0, 0);
        }
        {
            int r0 = w * 16 + half * 8;
            __builtin_amdgcn_global_load_lds(
                (const GLOBAL_AS unsigned int*)(Bb + (size_t)(r0 + rsub) * 1024 + csw * 8),
                (LDS_AS unsigned int*)(lB + r0 * 64), 16, 0, 0);
        }
    };

    f32x4 acc[4][4] = {};

    stage_half(0, 0, 0); stage_half(0, 0, 1);   // 6 loads: tile 0
    stage_half(1, 1, 0); stage_half(1, 1, 1);   // 6 loads: tile 1
    asm volatile("s_waitcnt vmcnt(6)" ::: "memory");   // tile 0 landed
    __builtin_amdgcn_s_barrier();

    for (int kt = 0; kt < 16; ++kt) {
        const int cur = kt % 3;
        const int nxt = (kt + 2) % 3;
        const bool pre = (kt < 14);
        const unsigned short* lA = lds + cur * 24576;
        const unsigned short* lB = lA + 16384;

#pragma unroll
        for (int kh = 0; kh < 2; ++kh) {
            // phase: ds_read subtile ∥ stage half-tile → barrier → MFMA
            bf16x8 af[4], bfr[4];
#pragma unroll
            for (int mi = 0; mi < 4; ++mi) {
                int row = wr * 64 + mi * 16 + l16;
                af[mi] = *(const bf16x8*)(lA + (size_t)row * 64 +
                                          (((kh * 4 + quad) ^ (row & 7)) * 8));
            }
#pragma unroll
            for (int ni = 0; ni < 4; ++ni) {
                int row = wc * 64 + ni * 16 + l16;
                bfr[ni] = *(const bf16x8*)(lB + (size_t)row * 64 +
                                           (((kh * 4 + quad) ^ (row & 7)) * 8));
            }
            if (pre) stage_half(kt + 2, nxt, kh);

            __builtin_amdgcn_s_barrier();
            asm volatile("s_waitcnt lgkmcnt(0)" ::: "memory");
            __builtin_amdgcn_sched_barrier(0);
            __builtin_amdgcn_s_setprio(1);
#pragma unroll
            for (int mi = 0; mi < 4; ++mi)
#pragma unroll
                for (int ni = 0; ni < 4; ++ni)
                    acc[mi][ni] = __builtin_amdgcn_mfma_f32_16x16x32_bf16(
                        af[mi], bfr[ni], acc[mi][ni], 0, 0, 0);
            __builtin_amdgcn_s_setprio(0);
            __builtin_amdgcn_sched_barrier(0);

            if (kh == 0) {
                __builtin_amdgcn_s_barrier();
            } else {
                // end of tile: tile kt+1 must be resident before next iter.
                if (kt < 14)       asm volatile("s_waitcnt vmcnt(6)" ::: "memory");
                else if (kt == 14) asm volatile("s_waitcnt vmcnt(0)" ::: "memory");
                if (kt < 15) __builtin_amdgcn_s_barrier();
            }
        }
    }

#pragma unroll
    for (int mi = 0; mi < 4; ++mi) {
        int rowb = bm + wr * 64 + mi * 16 + quad * 4;
#pragma unroll
        for (int ni = 0; ni < 4; ++ni) {
            int col = bn + wc * 64 + ni * 16 + l16;
            float bv_ = bias[col];
#pragma unroll
            for (int r = 0; r < 4; ++r) {
                int m = rowb + r;
                float vout = (acc[mi][ni][r] + bv_) * scale;
                int b = m >> 11, t = m & 2047, h = col >> 6, d = col & 63;
                if (!vmode) {
                    outp[((size_t)(b * 16 + h) * 2048 + t) * 64 + d] = f2bf(vout);
                } else {
                    outp[((size_t)(b * 16 + h) * 64 + d) * 2048 + t] = f2bf(vout);
                }
            }
        }
    }
}

// ---------------------------------------------------------------------------
// Output-projection GEMM (f32 out), same pipelined phase structure.
// ---------------------------------------------------------------------------
__global__ __launch_bounds__(512, 2) void out_gemm_kernel(
    const unsigned short* __restrict__ A,
    const unsigned short* __restrict__ Bw,
    const float* __restrict__ bias,
    float* __restrict__ outp)
{
    __shared__ __align__(16) unsigned short lds[3 * 24576];

    const int tid = threadIdx.x;
    const int w = tid >> 6, lane = tid & 63;
    const int quad = lane >> 4, l16 = lane & 15;
    const int wr = w >> 1, wc = w & 1;

    const int lin = blockIdx.x;
    const int r_ = lin & 7, s_ = lin >> 3;
    const int bm = (r_ * 4 + (s_ & 3)) * 256;
    const int bn = (s_ >> 2) * 128;

    const int rsub = lane >> 3;
    const int csw = (lane & 7) ^ rsub;

    auto stage_half = [&](int kt, int buf, int half) {
        unsigned short* lA = lds + buf * 24576;
        unsigned short* lB = lA + 16384;
        const unsigned short* Ab = A + (size_t)bm * 1024 + kt * 64;
        const unsigned short* Bb = Bw + (size_t)bn * 1024 + kt * 64;
#pragma unroll
        for (int j = 0; j < 2; ++j) {
            int r0 = w * 32 + (half * 2 + j) * 8;
            __builtin_amdgcn_global_load_lds(
                (const GLOBAL_AS unsigned int*)(Ab + (size_t)(r0 + rsub) * 1024 + csw * 8),
                (LDS_AS unsigned int*)(lA + r0 * 64), 16, 0, 0);
        }
        {
            int r0 = w * 16 + half * 8;
            __builtin_amdgcn_global_load_lds(
                (const GLOBAL_AS unsigned int*)(Bb + (size_t)(r0 + rsub) * 1024 + csw * 8),
                (LDS_AS unsigned int*)(lB + r0 * 64), 16, 0, 0);
        }
    };

    f32x4 acc[4][4] = {};

    stage_half(0, 0, 0); stage_half(0, 0, 1);
    stage_half(1, 1, 0); stage_half(1, 1, 1);
    asm volatile("s_waitcnt vmcnt(6)" ::: "memory");
    __builtin_amdgcn_s_barrier();

    for (int kt = 0; kt < 16; ++kt) {
        const int cur = kt % 3;
        const int nxt = (kt + 2) % 3;
        const bool pre = (kt < 14);
        const unsigned short* lA = lds + cur * 24576;
        const unsigned short* lB = lA + 16384;

#pragma unroll
        for (int kh = 0; kh < 2; ++kh) {
            bf16x8 af[4], bfr[4];
#pragma unroll
            for (int mi = 0; mi < 4; ++mi) {
                int row = wr * 64 + mi * 16 + l16;
                af[mi] = *(const bf16x8*)(lA + (size_t)row * 64 +
                                          (((kh * 4 + quad) ^ (row & 7)) * 8));
            }
#pragma unroll
            for (int ni = 0; ni < 4; ++ni) {
                int row = wc * 64 + ni * 16 + l16;
                bfr[ni] = *(const bf16x8*)(lB + (size_t)row * 64 +
                                           (((kh * 4 + quad) ^ (row & 7)) * 8));
            }
            if (pre) stage_half(kt + 2, nxt, kh);

            __builtin_amdgcn_s_barrier();
            asm volatile("s_waitcnt lgkmcnt(0)" ::: "memory");
            __builtin_amdgcn_sched_barrier(0);
            __builtin_amdgcn_s_setprio(1);
#pragma unroll
            for (int mi = 0; mi < 4; ++mi)
#pragma unroll
                for (int ni = 0; ni < 4; ++ni)
                    acc[mi][ni] = __builtin_amdgcn_mfma_f32_16x16x32_bf16(
                        af[mi], bfr[ni], acc[mi][ni], 0, 0, 0);
            __builtin_amdgcn_s_setprio(0);
            __builtin_amdgcn_sched_barrier(0);

            if (kh == 0) {
                __builtin_amdgcn_s_barrier();
            } else {
                if (kt < 14)       asm volatile("s_waitcnt vmcnt(6)" ::: "memory");
                else if (kt == 14) asm volatile("s_waitcnt vmcnt(0)" ::: "memory");
                if (kt < 15) __builtin_amdgcn_s_barrier();
            }
        }
    }

#pragma unroll
    for (int mi = 0; mi < 4; ++mi) {
        int rowb = bm + wr * 64 + mi * 16 + quad * 4;
#pragma unroll
        for (int ni = 0; ni < 4; ++ni) {
            int col = bn + wc * 64 + ni * 16 + l16;
            float bv_ = bias[col];
#pragma unroll
            for (int r = 0; r < 4; ++r)
                outp[(size_t)(rowb + r) * 1024 + col] = acc[mi][ni][r] + bv_;
        }
    }
}

// ---------------------------------------------------------------------------
// Flash attention v3 (causal, m=0 softmax, paired blocks).
// Round 6: 3-buffer depth-2 prefetch, counted vmcnt(4), raw s_barrier.
// ---------------------------------------------------------------------------
__global__ __launch_bounds__(256) void attn_kernel(
    const unsigned short* __restrict__ Qh,
    const unsigned short* __restrict__ Kh,
    const unsigned short* __restrict__ Vt,
    unsigned short* __restrict__ att)
{
    const int tid = threadIdx.x;
    const int w = tid >> 6, lane = tid & 63;
    const int qd = lane >> 4, l16 = lane & 15;
    const int bh = blockIdx.x;    // 0..63 (same-bh blocks -> same XCD)
    const int pairy = blockIdx.y; // 0..7

    const unsigned short* Qp = Qh + (size_t)bh * 2048 * 64;
    const unsigned short* Kp = Kh + (size_t)bh * 2048 * 64;
    const unsigned short* Vp = Vt + (size_t)bh * 64 * 2048;
    const int b = bh >> 4, h = bh & 15;

    __shared__ __align__(16) unsigned short Kl[3][64 * 64];
    __shared__ __align__(16) unsigned short Vl[3][64 * 64];
    __shared__ __align__(16) unsigned short Pl[4][2][16 * 64];

    auto stage = [&](int kt, int buf) {
#pragma unroll
        for (int j = 0; j < 2; ++j) {
            int r = w * 16 + j * 8 + (lane >> 3);
            int c = (lane & 7) ^ (r & 7);
            __builtin_amdgcn_global_load_lds(
                (const GLOBAL_AS unsigned int*)(Kp + (size_t)(kt * 64 + r) * 64 + c * 8),
                (LDS_AS unsigned int*)(&Kl[buf][(w * 16 + j * 8) * 64]), 16, 0, 0);
            __builtin_amdgcn_global_load_lds(
                (const GLOBAL_AS unsigned int*)(Vp + (size_t)r * 2048 + kt * 64 + c * 8),
                (LDS_AS unsigned int*)(&Vl[buf][(w * 16 + j * 8) * 64]), 16, 0, 0);
        }
    };

    auto run_phase = [&](int qblk) {
        const int wqbase = qblk * 128 + w * 32;
        const int ktmax = 2 * qblk + 1;

        bf16x8 qa[2][2];
#pragma unroll
        for (int qt = 0; qt < 2; ++qt)
#pragma unroll
            for (int ks = 0; ks < 2; ++ks)
                qa[qt][ks] = *(const bf16x8*)(Qp + (size_t)(wqbase + qt * 16 + l16) * 64 + ks * 32 + qd * 8);

        float lp[2] = {0.0f, 0.0f};
        f32x4 O[2][4] = {};

        __builtin_amdgcn_s_barrier();  // all waves done prior phase's LDS reads
        stage(0, 0);
        stage(1, 1);

        for (int kt = 0; kt <= ktmax; ++kt) {
            // tile kt resident; tile kt+1 (if any) stays in flight
            if (kt < ktmax) asm volatile("s_waitcnt vmcnt(4)" ::: "memory");
            else            asm volatile("s_waitcnt vmcnt(0)" ::: "memory");
            __builtin_amdgcn_s_barrier();
            if (kt + 2 <= ktmax) stage(kt + 2, (kt + 2) % 3);

            if (kt * 64 <= wqbase + 31) {  // wave-uniform skip of masked tiles
                const unsigned short* kl = &Kl[kt % 3][0];
                const unsigned short* vl = &Vl[kt % 3][0];

                bf16x8 kf[4][2];
#pragma unroll
                for (int nt = 0; nt < 4; ++nt)
#pragma unroll
                    for (int ks = 0; ks < 2; ++ks)
                        kf[nt][ks] = *(const bf16x8*)(kl + (nt * 16 + l16) * 64 +
                                                      (((ks * 4 + qd) ^ (l16 & 7)) * 8));

                f32x4 S[2][4];
#pragma unroll
                for (int qt = 0; qt < 2; ++qt)
#pragma unroll
                    for (int nt = 0; nt < 4; ++nt) {
                        f32x4 a = {};
                        a = __builtin_amdgcn_mfma_f32_16x16x32_bf16(kf[nt][0], qa[qt][0], a, 0, 0, 0);
                        a = __builtin_amdgcn_mfma_f32_16x16x32_bf16(kf[nt][1], qa[qt][1], a, 0, 0, 0);
                        S[qt][nt] = a;
                    }

                if (kt * 64 + 63 > wqbase) {
#pragma unroll
                    for (int qt = 0; qt < 2; ++qt) {
                        int qrow = wqbase + qt * 16 + l16;
#pragma unroll
                        for (int nt = 0; nt < 4; ++nt) {
                            int kbase = kt * 64 + nt * 16 + qd * 4;
#pragma unroll
                            for (int r = 0; r < 4; ++r)
                                if (kbase + r > qrow) S[qt][nt][r] = -INFINITY;
                        }
                    }
                }

#pragma unroll
                for (int qt = 0; qt < 2; ++qt) {
                    float s0 = 0.0f;
#pragma unroll
                    for (int nt = 0; nt < 4; ++nt)
#pragma unroll
                        for (int r = 0; r < 4; ++r) {
                            float e = __builtin_amdgcn_exp2f(S[qt][nt][r]);
                            S[qt][nt][r] = e;
                            s0 += e;
                        }
                    lp[qt] += s0;
                }

#pragma unroll
                for (int qt = 0; qt < 2; ++qt) {
                    unsigned short* pw = &Pl[w][qt][0];
#pragma unroll
                    for (int nt = 0; nt < 4; ++nt) {
                        uint2 pv;
                        pv.x = pack_trunc(S[qt][nt][0], S[qt][nt][1]);
                        pv.y = pack_trunc(S[qt][nt][2], S[qt][nt][3]);
                        int chunk = (2 * nt + (qd >> 1)) ^ (l16 & 7);
                        *(uint2*)(pw + l16 * 64 + chunk * 8 + (qd & 1) * 4) = pv;
                    }
                }
                asm volatile("s_waitcnt lgkmcnt(0)" ::: "memory");

                bf16x8 pa[2][2];
#pragma unroll
                for (int qt = 0; qt < 2; ++qt)
#pragma unroll
                    for (int s = 0; s < 2; ++s)
                        pa[qt][s] = *(const bf16x8*)(&Pl[w][qt][0] + l16 * 64 +
                                                     (((s * 4 + qd) ^ (l16 & 7)) * 8));

                bf16x8 vf[2][4];
#pragma unroll
                for (int s = 0; s < 2; ++s)
#pragma unroll
                    for (int dh = 0; dh < 4; ++dh)
                        vf[s][dh] = *(const bf16x8*)(vl + (dh * 16 + l16) * 64 +
                                                     (((s * 4 + qd) ^ (l16 & 7)) * 8));
#pragma unroll
                for (int qt = 0; qt < 2; ++qt)
#pragma unroll
                    for (int dh = 0; dh < 4; ++dh) {
                        O[qt][dh] = __builtin_amdgcn_mfma_f32_16x16x32_bf16(pa[qt][0], vf[0][dh], O[qt][dh], 0, 0, 0);
                        O[qt][dh] = __builtin_amdgcn_mfma_f32_16x16x32_bf16(pa[qt][1], vf[1][dh], O[qt][dh], 0, 0, 0);
                    }
            }
        }

#pragma unroll
        for (int qt = 0; qt < 2; ++qt) {
            float lsum = lp[qt];
            lsum += __shfl_xor(lsum, 16, 64);
            lsum += __shfl_xor(lsum, 32, 64);
            float linv = 1.0f / lsum;
#pragma unroll
            for (int r = 0; r < 4; ++r) {
                float lC = __shfl(linv, qd * 4 + r, 64);
                int t = wqbase + qt * 16 + qd * 4 + r;
#pragma unroll
                for (int dh = 0; dh < 4; ++dh) {
                    size_t idx = (size_t)(b * 2048 + t) * 1024 + h * 64 + dh * 16 + l16;
                    att[idx] = f2bf(O[qt][dh][r] * lC);
                }
            }
        }
    };

    run_phase(15 - pairy);  // heavy half
    run_phase(pairy);       // light half -> uniform 36 tiles per block
}

// ---------------------------------------------------------------------------
// Launch
// ---------------------------------------------------------------------------
extern "C" void kernel_launch(void* const* d_in, const int* in_sizes, int n_in,
                              void* d_out, int out_size, void* d_ws, size_t ws_size,
                              hipStream_t stream)
{
    const float* q = (const float*)d_in[0];
    const float* k = (const float*)d_in[1];
    const float* v = (const float*)d_in[2];
    const float* wq_w = (const float*)d_in[5];
    const float* wq_b = (const float*)d_in[6];
    const float* wk_w = (const float*)d_in[7];
    const float* wk_b = (const float*)d_in[8];
    const float* wv_w = (const float*)d_in[9];
    const float* wv_b = (const float*)d_in[10];
    const float* wo_w = (const float*)d_in[11];
    const float* wo_b = (const float*)d_in[12];

    unsigned short* ws = (unsigned short*)d_ws;
    unsigned short* xq  = ws;                    // 8M
    unsigned short* wqc = ws + 25165824;         // wq,wk,wv contiguous 1M each
    unsigned short* woc = ws + 28311552;
    unsigned short* Qhp = ws + 29360128;         // Qh,Kh,Vt contiguous 8M each
    unsigned short* Khp = ws + 37748736;
    unsigned short* Vtp = ws + 46137344;
    unsigned short* att = xq;  // xq dead after QKV projections

    (void)in_sizes; (void)n_in; (void)out_size; (void)ws_size;

    cast_all_kernel<<<28672, 256, 0, stream>>>(q, k, v, wq_w, wk_w, wv_w, wo_w, ws);

    qkv_gemm_kernel<<<dim3(256, 3), 512, 0, stream>>>(
        xq, wqc, wq_b, wk_b, wv_b, Qhp, 0.1803368801f);

    attn_kernel<<<dim3(64, 8), 256, 0, stream>>>(Qhp, Khp, Vtp, att);

    out_gemm_kernel<<<dim3(256), 512, 0, stream>>>(att, woc, wo_b, (float*)d_out);
}